// Round 2
// baseline (29039.221 us; speedup 1.0000x reference)
//
#include <hip/hip_runtime.h>
#include <hip/hip_fp16.h>
#include <hip/hip_cooperative_groups.h>

namespace cg = cooperative_groups;

#define HID    1024
#define G4     4096
#define TT     512
#define BB     8
#define VOCABN 32000
#define CH     72     // LDS chunk stride (halves) per 64-col chunk: 36 dw -> 2-way banks
#define BROW   1160   // LDS halves per batch row: 16*CH + 8 pad (16B-aligned rows)

typedef _Float16 f16x2 __attribute__((ext_vector_type(2)));
typedef _Float16 f16x8 __attribute__((ext_vector_type(8)));
typedef float    f32x4 __attribute__((ext_vector_type(4)));

union F4H { f32x4 f; f16x2 h[4]; };

__device__ __forceinline__ float dot2f(f16x2 a, f16x2 b, float c) {
#if __has_builtin(__builtin_amdgcn_fdot2)
  return __builtin_amdgcn_fdot2(a, b, c, false);
#else
  return c + (float)a[0] * (float)b[0] + (float)a[1] * (float)b[1];
#endif
}
__device__ __forceinline__ float sigf(float x) { return 1.0f / (1.0f + expf(-x)); }

// ---------------- f32 -> f16 convert ----------------
__global__ void cvt_f16_kernel(const float* __restrict__ src, __half* __restrict__ dst, int n4) {
  int i = blockIdx.x * blockDim.x + threadIdx.x;
  int stride = gridDim.x * blockDim.x;
  for (; i < n4; i += stride) {
    f32x4 v = ((const f32x4*)src)[i];
    ((__half2*)dst)[2 * i]     = __floats2half2_rn(v[0], v[1]);
    ((__half2*)dst)[2 * i + 1] = __floats2half2_rn(v[2], v[3]);
  }
}

// ---------------- embedding gather: xe[t*8+b] = emb16[x[b][t]] ----------------
__global__ void gather_kernel(const int* __restrict__ x, const __half* __restrict__ emb,
                              __half* __restrict__ xe) {
  int gid = blockIdx.x * 256 + threadIdx.x;   // 4096 rows * 128 chunks of 16B
  int row = gid >> 7, ch = gid & 127;
  int t = row >> 3, b = row & 7;
  int tok = x[b * TT + t];
  ((f32x4*)(xe + (size_t)row * HID))[ch] = ((const f32x4*)(emb + (size_t)tok * HID))[ch];
}

__device__ __forceinline__ void storeC(float* p, float v)  { *p = v; }
__device__ __forceinline__ void storeC(__half* p, float v) { *p = __float2half(v); }

// ------- 128x128 f16 MFMA GEMM: C[M,N] = A[M,1024] * B[N,1024]^T (+bias) -------
template <typename CT>
__global__ void __launch_bounds__(256) gemm_f16_kernel(
    const _Float16* __restrict__ A, const _Float16* __restrict__ B,
    CT* __restrict__ C, const float* __restrict__ bias, int N)
{
  __shared__ _Float16 As[128 * 40];
  __shared__ _Float16 Bs[128 * 40];
  const int tid = threadIdx.x;
  const int tn = blockIdx.x, tm = blockIdx.y;
  const int wave = tid >> 6, lane = tid & 63;
  const int wm = wave >> 1, wn = wave & 1;
  const int lr = lane & 15, lk = ((lane >> 4) << 3);
  const _Float16* Ab = A + (size_t)tm * 128 * HID;
  const _Float16* Bb = B + (size_t)tn * 128 * HID;
  const int r0 = tid >> 2, c8 = (tid & 3) * 8;
  f32x4 acc[4][4] = {};
  f32x4 a0r, a1r, b0r, b1r;
  a0r = *(const f32x4*)(Ab + (size_t)r0 * HID + c8);
  a1r = *(const f32x4*)(Ab + (size_t)(64 + r0) * HID + c8);
  b0r = *(const f32x4*)(Bb + (size_t)r0 * HID + c8);
  b1r = *(const f32x4*)(Bb + (size_t)(64 + r0) * HID + c8);
  for (int kt = 0; kt < 32; ++kt) {
    __syncthreads();
    *(f32x4*)(As + (size_t)r0 * 40 + c8)        = a0r;
    *(f32x4*)(As + (size_t)(64 + r0) * 40 + c8) = a1r;
    *(f32x4*)(Bs + (size_t)r0 * 40 + c8)        = b0r;
    *(f32x4*)(Bs + (size_t)(64 + r0) * 40 + c8) = b1r;
    __syncthreads();
    if (kt < 31) {
      int ko = (kt + 1) * 32 + c8;
      a0r = *(const f32x4*)(Ab + (size_t)r0 * HID + ko);
      a1r = *(const f32x4*)(Ab + (size_t)(64 + r0) * HID + ko);
      b0r = *(const f32x4*)(Bb + (size_t)r0 * HID + ko);
      b1r = *(const f32x4*)(Bb + (size_t)(64 + r0) * HID + ko);
    }
    f16x8 af[4], bf[4];
    #pragma unroll
    for (int m = 0; m < 4; ++m) af[m] = *(const f16x8*)(As + (wm * 64 + m * 16 + lr) * 40 + lk);
    #pragma unroll
    for (int n = 0; n < 4; ++n) bf[n] = *(const f16x8*)(Bs + (wn * 64 + n * 16 + lr) * 40 + lk);
    #pragma unroll
    for (int m = 0; m < 4; ++m)
      #pragma unroll
      for (int n = 0; n < 4; ++n)
        acc[m][n] = __builtin_amdgcn_mfma_f32_16x16x32_f16(af[m], bf[n], acc[m][n], 0, 0, 0);
  }
  const int mrow = ((lane >> 4) << 2);
  #pragma unroll
  for (int n = 0; n < 4; ++n) {
    int gc = tn * 128 + wn * 64 + n * 16 + lr;
    float bc = bias ? bias[gc] : 0.0f;
    #pragma unroll
    for (int m = 0; m < 4; ++m) {
      int gr = tm * 128 + wm * 64 + m * 16 + mrow;
      #pragma unroll
      for (int r = 0; r < 4; ++r)
        storeC(C + (size_t)(gr + r) * N + gc, acc[m][n][r] + bc);
    }
  }
}

// ---------------- persistent LSTM ----------------
// 256 WGs x 256 threads, >=2 blocks/CU schedulable. WG owns 4 units/layer.
// Weights in VGPRs (96 half2/thread). h state global, [b][u] f16, double-buffered.
// Tick tau: layer0 -> h0[tau] (tau<512); layer1 -> h1[tau-1] (tau>=1).
template <bool COOP>
__global__ void __launch_bounds__(256, 2) lstm_kernel(
    const __half* __restrict__ wh0, const __half* __restrict__ wx1, const __half* __restrict__ wh1,
    const __half* __restrict__ X0, const float* __restrict__ wxb1,
    __half* __restrict__ h0t, __half* __restrict__ h1t, float* __restrict__ cgl,
    __half* __restrict__ outf, float* __restrict__ hc_out,
    int tau0, int tau1)
{
  __shared__ __half h0s[BB * BROW];
  __shared__ __half h1s[BB * BROW];
  __shared__ float  gx[32 * 8];

  const int tid = threadIdx.x;
  const int u0  = blockIdx.x * 4;
  const int rg  = tid >> 4, ks = tid & 15;   // rg: g=rg&3, uu=rg>>2 ; ks: 64-col slice

  // ---- pin weights in registers: 3 x 32 half2 per thread ----
  f16x2 w0[32], w1[32], w2[32];
  {
    const int r = (rg & 3) * HID + u0 + (rg >> 2);
    const __half* p0 = wh0 + (size_t)r * HID + ks * 64;
    const __half* p1 = wx1 + (size_t)r * HID + ks * 64;
    const __half* p2 = wh1 + (size_t)r * HID + ks * 64;
    #pragma unroll
    for (int q = 0; q < 8; ++q) {
      F4H t0, t1, t2;
      t0.f = *(const f32x4*)(p0 + q * 8);
      t1.f = *(const f32x4*)(p1 + q * 8);
      t2.f = *(const f32x4*)(p2 + q * 8);
      #pragma unroll
      for (int j = 0; j < 4; ++j) {
        w0[q * 4 + j] = t0.h[j]; w1[q * 4 + j] = t1.h[j]; w2[q * 4 + j] = t2.h[j];
      }
    }
  }

  float bi0 = 0, bi1 = 0, bi2 = 0, bi3 = 0;
  if (tid >= 32 && tid < 64) {
    int uu = (tid >> 3) & 3, u = u0 + uu;
    bi0 = wxb1[u]; bi1 = wxb1[HID + u]; bi2 = wxb1[2 * HID + u]; bi3 = wxb1[3 * HID + u];
  }

  for (int tau = tau0; tau < tau1; ++tau) {
    float x0r0 = 0, x0r1 = 0, x0r2 = 0, x0r3 = 0;
    if (tid < 32 && tau < TT) {
      int b = tid & 7, uu = (tid >> 3) & 3;
      const __half* xp = X0 + (size_t)(tau * BB + b) * G4 + u0 + uu;
      x0r0 = __half2float(xp[0]);       x0r1 = __half2float(xp[HID]);
      x0r2 = __half2float(xp[2 * HID]); x0r3 = __half2float(xp[3 * HID]);
    }
    // stage h0[tau-1], h1[tau-2] into chunk-padded LDS
    {
      const f32x4* s0 = (const f32x4*)(h0t + ((tau - 1) & 1) * (HID * BB));
      const f32x4* s1 = (const f32x4*)(h1t + (tau & 1) * (HID * BB));
      #pragma unroll
      for (int i = 0; i < 4; ++i) {
        int k = i * 256 + tid;            // 1024 float4 per h buffer
        int b = k >> 7, c = k & 127;
        int d = b * BROW + (c >> 3) * CH + (c & 7) * 8;
        *(f32x4*)(h0s + d) = s0[k];
        *(f32x4*)(h1s + d) = s1[k];
      }
    }
    __syncthreads();

    // ---- dots: acc0 = wh0 . h0 ; acc1 = wx1 . h0 + wh1 . h1 (per batch) ----
    float acc0[BB], acc1[BB];
    #pragma unroll
    for (int b = 0; b < BB; ++b) {
      const __half* hp0 = h0s + b * BROW + ks * CH;
      f16x2 hh[32];
      #pragma unroll
      for (int q = 0; q < 8; ++q) {
        F4H t; t.f = *(const f32x4*)(hp0 + q * 8);
        hh[q * 4 + 0] = t.h[0]; hh[q * 4 + 1] = t.h[1];
        hh[q * 4 + 2] = t.h[2]; hh[q * 4 + 3] = t.h[3];
      }
      float a0 = 0.f, a1 = 0.f;
      #pragma unroll
      for (int j = 0; j < 32; ++j) { a0 = dot2f(w0[j], hh[j], a0); a1 = dot2f(w1[j], hh[j], a1); }
      const __half* hp1 = h1s + b * BROW + ks * CH;
      #pragma unroll
      for (int q = 0; q < 8; ++q) {
        F4H t; t.f = *(const f32x4*)(hp1 + q * 8);
        hh[q * 4 + 0] = t.h[0]; hh[q * 4 + 1] = t.h[1];
        hh[q * 4 + 2] = t.h[2]; hh[q * 4 + 3] = t.h[3];
      }
      #pragma unroll
      for (int j = 0; j < 32; ++j) { a1 = dot2f(w2[j], hh[j], a1); }
      acc0[b] = a0; acc1[b] = a1;
    }
    // reduce over the 16 k-slice lanes
    #pragma unroll
    for (int m = 1; m <= 8; m <<= 1) {
      #pragma unroll
      for (int b = 0; b < BB; ++b) {
        acc0[b] += __shfl_xor(acc0[b], m, 64);
        acc1[b] += __shfl_xor(acc1[b], m, 64);
      }
    }
    if (ks == 0) {
      #pragma unroll
      for (int b = 0; b < BB; ++b) {
        gx[rg * 8 + b]        = acc0[b];
        gx[(16 + rg) * 8 + b] = acc1[b];
      }
    }
    __syncthreads();

    // ---- cell/hidden update: 64 threads = 2 layers x 4 units x 8 batch ----
    if (tid < 64) {
      const int l = tid >> 5, uu = (tid >> 3) & 3, b = tid & 7;
      const bool act = (l == 0) ? (tau < TT) : (tau >= 1);
      if (act) {
        const int u = u0 + uu;
        const float* gp = gx + ((l << 4) + (uu << 2)) * 8 + b;
        float gi = gp[0], gf = gp[8], gg_ = gp[16], go = gp[24];
        if (l == 0) { gi += x0r0; gf += x0r1; gg_ += x0r2; go += x0r3; }
        else        { gi += bi0;  gf += bi1;  gg_ += bi2;  go += bi3;  }
        float* cp = cgl + (size_t)l * (HID * BB) + u * BB + b;
        float co = *cp;
        float cn = sigf(gf) * co + sigf(gi) * tanhf(gg_);
        float hn = sigf(go) * tanhf(co);   // quirk: tanh of OLD cell
        *cp = cn;
        __half hv = __float2half(hn);
        if (l == 0) {
          h0t[(tau & 1) * (HID * BB) + b * HID + u] = hv;
        } else {
          h1t[((tau - 1) & 1) * (HID * BB) + b * HID + u] = hv;
          outf[((size_t)b * TT + (tau - 1)) * HID + u] = hv;
        }
      }
    }
    if constexpr (COOP) {
      __threadfence();
      cg::this_grid().sync();
    }
  }

  // final h, c (only when the loop covered the last tick)
  if (tau1 > TT && tid < 64) {
    const int l = tid >> 5, uu = (tid >> 3) & 3, b = tid & 7;
    const int u = u0 + uu;
    float hv = __half2float((l == 0 ? h0t : h1t)[(HID * BB) + b * HID + u]);
    hc_out[(size_t)l * (BB * HID) + b * HID + u] = hv;
    hc_out[2 * (BB * HID) + (size_t)l * (BB * HID) + b * HID + u] =
        cgl[(size_t)l * (HID * BB) + u * BB + b];
  }
}

extern "C" void kernel_launch(void* const* d_in, const int* in_sizes, int n_in,
                              void* d_out, int out_size, void* d_ws, size_t ws_size,
                              hipStream_t stream) {
  (void)in_sizes; (void)n_in; (void)out_size; (void)ws_size;
  const int*   x    = (const int*)  d_in[0];
  const float* embW = (const float*)d_in[1];
  const float* wxw  = (const float*)d_in[2];
  const float* wxb  = (const float*)d_in[3];
  const float* whw  = (const float*)d_in[4];
  float* out = (float*)d_out;

  char* ws = (char*)d_ws;
  size_t off = 0;
  auto alloc = [&](size_t bytes) { char* p = ws + off; off += (bytes + 255) & ~(size_t)255; return p; };
  __half* emb16 = (__half*)alloc((size_t)VOCABN * HID * 2);
  __half* xe16  = (__half*)alloc((size_t)4096 * HID * 2);
  __half* wxw16 = (__half*)alloc((size_t)2 * G4 * HID * 2);
  __half* whw16 = (__half*)alloc((size_t)2 * G4 * HID * 2);
  __half* X0    = (__half*)alloc((size_t)4096 * G4 * 2);
  __half* outf  = (__half*)alloc((size_t)4096 * HID * 2);
  __half* h0t   = (__half*)alloc((size_t)2 * HID * BB * 2);
  __half* h1t   = (__half*)alloc((size_t)2 * HID * BB * 2);
  float*  cgl   = (float*) alloc((size_t)2 * HID * BB * 4);

  cvt_f16_kernel<<<2048, 256, 0, stream>>>(embW, emb16, VOCABN * HID / 4);
  cvt_f16_kernel<<<1024, 256, 0, stream>>>(wxw, wxw16, 2 * G4 * HID / 4);
  cvt_f16_kernel<<<1024, 256, 0, stream>>>(whw, whw16, 2 * G4 * HID / 4);
  gather_kernel<<<2048, 256, 0, stream>>>(x, emb16, xe16);
  hipMemsetAsync(h0t, 0, (size_t)2 * HID * BB * 2, stream);
  hipMemsetAsync(h1t, 0, (size_t)2 * HID * BB * 2, stream);
  hipMemsetAsync(cgl, 0, (size_t)2 * HID * BB * 4, stream);

  // X0 = xe @ wx0^T + b0   (f16 out)
  gemm_f16_kernel<__half><<<dim3(32, 32), 256, 0, stream>>>(
      (const _Float16*)xe16, (const _Float16*)wxw16, X0, wxb, G4);

  const __half* wh0 = whw16;
  const __half* wx1 = wxw16 + (size_t)G4 * HID;
  const __half* wh1 = whw16 + (size_t)G4 * HID;
  const __half* X0c = X0;
  const float*  wxb1 = wxb + G4;
  float* hc = out + (size_t)4096 * VOCABN;
  int tb = 0, te = TT + 1;
  void* args[] = {(void*)&wh0, (void*)&wx1, (void*)&wh1, (void*)&X0c, (void*)&wxb1,
                  (void*)&h0t, (void*)&h1t, (void*)&cgl, (void*)&outf, (void*)&hc,
                  (void*)&tb, (void*)&te};
  hipError_t rc = hipLaunchCooperativeKernel(
      reinterpret_cast<void*>(&lstm_kernel<true>), dim3(256), dim3(256), args, 0, stream);
  if (rc != hipSuccess) {
    // fallback: per-timestep launches (slow but correct)
    for (int tau = 0; tau <= TT; ++tau)
      lstm_kernel<false><<<256, 256, 0, stream>>>(wh0, wx1, wh1, X0c, wxb1,
                                                  h0t, h1t, cgl, outf, hc, tau, tau + 1);
  }

  // logits = out_h1 @ emb^T  (f32 out)
  gemm_f16_kernel<float><<<dim3(250, 32), 256, 0, stream>>>(
      (const _Float16*)outf, (const _Float16*)emb16, out, nullptr, VOCABN);
}

// Round 4
// 7077.931 us; speedup vs baseline: 4.1028x; 4.1028x over previous
//
#include <hip/hip_runtime.h>
#include <hip/hip_fp16.h>

#define HID    1024
#define G4     4096
#define TT     512
#define BB     8
#define VOCABN 32000
#define CH     72     // LDS chunk stride (halves) per 64-col chunk
#define BROW   1160   // LDS halves per batch row: 16*CH + 8 pad

typedef _Float16 f16x2 __attribute__((ext_vector_type(2)));
typedef _Float16 f16x8 __attribute__((ext_vector_type(8)));
typedef float    f32x4 __attribute__((ext_vector_type(4)));
typedef unsigned long long u64;

union F4H { f32x4 f; f16x2 h[4]; };

__device__ __forceinline__ float dot2f(f16x2 a, f16x2 b, float c) {
#if __has_builtin(__builtin_amdgcn_fdot2)
  return __builtin_amdgcn_fdot2(a, b, c, false);
#else
  return c + (float)a[0] * (float)b[0] + (float)a[1] * (float)b[1];
#endif
}
__device__ __forceinline__ float sigf(float x) { return 1.0f / (1.0f + expf(-x)); }

// ---------------- f32 -> f16 convert ----------------
__global__ void cvt_f16_kernel(const float* __restrict__ src, __half* __restrict__ dst, int n4) {
  int i = blockIdx.x * blockDim.x + threadIdx.x;
  int stride = gridDim.x * blockDim.x;
  for (; i < n4; i += stride) {
    f32x4 v = ((const f32x4*)src)[i];
    ((__half2*)dst)[2 * i]     = __floats2half2_rn(v[0], v[1]);
    ((__half2*)dst)[2 * i + 1] = __floats2half2_rn(v[2], v[3]);
  }
}

// ---------------- embedding gather: xe[t*8+b] = emb16[x[b][t]] ----------------
__global__ void gather_kernel(const int* __restrict__ x, const __half* __restrict__ emb,
                              __half* __restrict__ xe) {
  int gid = blockIdx.x * 256 + threadIdx.x;   // 4096 rows * 128 chunks of 16B
  int row = gid >> 7, ch = gid & 127;
  int t = row >> 3, b = row & 7;
  int tok = x[b * TT + t];
  ((f32x4*)(xe + (size_t)row * HID))[ch] = ((const f32x4*)(emb + (size_t)tok * HID))[ch];
}

__device__ __forceinline__ void storeC(float* p, float v)  { *p = v; }
__device__ __forceinline__ void storeC(__half* p, float v) { *p = __float2half(v); }

// ------- 128x128 f16 MFMA GEMM: C = A[M,1024] * B[N,1024]^T (+bias) -------
// XL=true: write to X0T layout [tau][gate][unit][batch] (half)
template <typename CT, bool XL>
__global__ void __launch_bounds__(256) gemm_f16_kernel(
    const _Float16* __restrict__ A, const _Float16* __restrict__ B,
    CT* __restrict__ C, const float* __restrict__ bias, int N)
{
  __shared__ _Float16 As[128 * 40];
  __shared__ _Float16 Bs[128 * 40];
  const int tid = threadIdx.x;
  const int tn = blockIdx.x, tm = blockIdx.y;
  const int wave = tid >> 6, lane = tid & 63;
  const int wm = wave >> 1, wn = wave & 1;
  const int lr = lane & 15, lk = ((lane >> 4) << 3);
  const _Float16* Ab = A + (size_t)tm * 128 * HID;
  const _Float16* Bb = B + (size_t)tn * 128 * HID;
  const int r0 = tid >> 2, c8 = (tid & 3) * 8;
  f32x4 acc[4][4] = {};
  f32x4 a0r, a1r, b0r, b1r;
  a0r = *(const f32x4*)(Ab + (size_t)r0 * HID + c8);
  a1r = *(const f32x4*)(Ab + (size_t)(64 + r0) * HID + c8);
  b0r = *(const f32x4*)(Bb + (size_t)r0 * HID + c8);
  b1r = *(const f32x4*)(Bb + (size_t)(64 + r0) * HID + c8);
  for (int kt = 0; kt < 32; ++kt) {
    __syncthreads();
    *(f32x4*)(As + (size_t)r0 * 40 + c8)        = a0r;
    *(f32x4*)(As + (size_t)(64 + r0) * 40 + c8) = a1r;
    *(f32x4*)(Bs + (size_t)r0 * 40 + c8)        = b0r;
    *(f32x4*)(Bs + (size_t)(64 + r0) * 40 + c8) = b1r;
    __syncthreads();
    if (kt < 31) {
      int ko = (kt + 1) * 32 + c8;
      a0r = *(const f32x4*)(Ab + (size_t)r0 * HID + ko);
      a1r = *(const f32x4*)(Ab + (size_t)(64 + r0) * HID + ko);
      b0r = *(const f32x4*)(Bb + (size_t)r0 * HID + ko);
      b1r = *(const f32x4*)(Bb + (size_t)(64 + r0) * HID + ko);
    }
    f16x8 af[4], bf[4];
    #pragma unroll
    for (int m = 0; m < 4; ++m) af[m] = *(const f16x8*)(As + (wm * 64 + m * 16 + lr) * 40 + lk);
    #pragma unroll
    for (int n = 0; n < 4; ++n) bf[n] = *(const f16x8*)(Bs + (wn * 64 + n * 16 + lr) * 40 + lk);
    #pragma unroll
    for (int m = 0; m < 4; ++m)
      #pragma unroll
      for (int n = 0; n < 4; ++n)
        acc[m][n] = __builtin_amdgcn_mfma_f32_16x16x32_f16(af[m], bf[n], acc[m][n], 0, 0, 0);
  }
  const int mrow = ((lane >> 4) << 2);
  #pragma unroll
  for (int n = 0; n < 4; ++n) {
    int gc = tn * 128 + wn * 64 + n * 16 + lr;
    float bc = bias ? bias[gc] : 0.0f;
    #pragma unroll
    for (int m = 0; m < 4; ++m) {
      int gr0 = tm * 128 + wm * 64 + m * 16 + mrow;
      #pragma unroll
      for (int r = 0; r < 4; ++r) {
        float v = acc[m][n][r] + bc;
        if constexpr (XL) {
          int gr = gr0 + r;
          int idx = ((gr >> 3) * 4 + (gc >> 10)) * 8192 + (gc & 1023) * 8 + (gr & 7);
          storeC(C + idx, v);
        } else {
          storeC(C + (size_t)(gr0 + r) * N + gc, v);
        }
      }
    }
  }
}

// ---- two-level fence-free grid barrier (relaxed agent atomics, LLC-coherent) ----
// bs[0..7] group arrive counters, bs[8] root, bs[9] gen. All monotonic, no resets.
// Spin has a generous timeout (~5ms) so a broken barrier produces a wrong answer
// instead of a GPU hang / dead container.
__device__ __forceinline__ void gbar(unsigned* bs, int epoch) {
  __syncthreads();   // compiler drains vmcnt before s_barrier -> all waves' stores complete
  if (threadIdx.x == 0) {
    asm volatile("s_waitcnt vmcnt(0)" ::: "memory");
    unsigned g = blockIdx.x & 7u;
    unsigned old = __hip_atomic_fetch_add(&bs[g], 1u, __ATOMIC_RELAXED, __HIP_MEMORY_SCOPE_AGENT);
    if ((old & 31u) == 31u) {
      unsigned r = __hip_atomic_fetch_add(&bs[8], 1u, __ATOMIC_RELAXED, __HIP_MEMORY_SCOPE_AGENT);
      if ((r & 7u) == 7u)
        __hip_atomic_store(&bs[9], (unsigned)epoch, __ATOMIC_RELAXED, __HIP_MEMORY_SCOPE_AGENT);
    }
    int guard = 0;
    while ((int)__hip_atomic_load(&bs[9], __ATOMIC_RELAXED, __HIP_MEMORY_SCOPE_AGENT) < epoch) {
      __builtin_amdgcn_s_sleep(2);
      if (++guard > 100000) break;   // ~5ms failsafe: fail loud, not hung
    }
    asm volatile("" ::: "memory");
  }
  __syncthreads();
}

// ---------------- persistent LSTM ----------------
// 256 WGs x 256 threads. WG owns 4 units/layer; weights in regs (96 f16x2 x3).
// h state global f16 double-buffered, exchanged via relaxed agent atomics (LLC).
// Tick tau: layer0 -> h0[tau] (tau<512); layer1 -> h1[tau-1] (tau>=1).
template <bool COOP>
__global__ void __launch_bounds__(256, 2) lstm_kernel(
    const __half* __restrict__ wh0, const __half* __restrict__ wx1, const __half* __restrict__ wh1,
    const __half* __restrict__ X0T, const float* __restrict__ wxb1,
    __half* __restrict__ h0t, __half* __restrict__ h1t, float* __restrict__ cgl,
    __half* __restrict__ outf, float* __restrict__ hc_out, unsigned* __restrict__ bs,
    int tau0, int tau1)
{
  __shared__ __half h0s[BB * BROW];
  __shared__ __half h1s[BB * BROW];
  __shared__ float  gx[32 * 8];

  const int tid = threadIdx.x;
  const int u0  = blockIdx.x * 4;
  const int rg  = tid >> 4, ks = tid & 15;   // rg: g=rg&3, uu=rg>>2 ; ks: 64-col k-slice

  // ---- pin weights in registers: 3 x 32 f16x2 per thread ----
  f16x2 w0[32], w1[32], w2[32];
  {
    const int r = (rg & 3) * HID + u0 + (rg >> 2);
    const __half* p0 = wh0 + (size_t)r * HID + ks * 64;
    const __half* p1 = wx1 + (size_t)r * HID + ks * 64;
    const __half* p2 = wh1 + (size_t)r * HID + ks * 64;
    #pragma unroll
    for (int q = 0; q < 8; ++q) {
      F4H t0, t1, t2;
      t0.f = *(const f32x4*)(p0 + q * 8);
      t1.f = *(const f32x4*)(p1 + q * 8);
      t2.f = *(const f32x4*)(p2 + q * 8);
      #pragma unroll
      for (int j = 0; j < 4; ++j) {
        w0[q * 4 + j] = t0.h[j]; w1[q * 4 + j] = t1.h[j]; w2[q * 4 + j] = t2.h[j];
      }
    }
  }

  float bi0 = 0, bi1 = 0, bi2 = 0, bi3 = 0;
  if (tid >= 32 && tid < 64) {
    int uu = (tid >> 3) & 3, u = u0 + uu;
    bi0 = wxb1[u]; bi1 = wxb1[HID + u]; bi2 = wxb1[2 * HID + u]; bi3 = wxb1[3 * HID + u];
  }

  for (int tau = tau0; tau < tau1; ++tau) {
    // X0 prefetch (coalesced: 32 consecutive halves per gate)
    float x0r0 = 0, x0r1 = 0, x0r2 = 0, x0r3 = 0;
    if (tid < 32 && tau < TT) {
      const __half* xp = X0T + (size_t)tau * 4 * 8192 + u0 * 8 + tid;
      x0r0 = __half2float(xp[0]);
      x0r1 = __half2float(xp[8192]);
      x0r2 = __half2float(xp[2 * 8192]);
      x0r3 = __half2float(xp[3 * 8192]);
    }
    // stage h0[tau-1], h1[tau-2] into chunk-padded LDS (coherent u64 loads from LLC)
    {
      const u64* s0 = (const u64*)(h0t + ((tau - 1) & 1) * (HID * BB));
      const u64* s1 = (const u64*)(h1t + (tau & 1) * (HID * BB));
      #pragma unroll
      for (int i = 0; i < 8; ++i) {
        int k = i * 256 + tid;           // 2048 u64 granules per buffer
        int b = k >> 8, q = k & 255;
        int d = b * BROW + (q >> 4) * CH + (q & 15) * 4;
        u64 v0 = __hip_atomic_load(&s0[k], __ATOMIC_RELAXED, __HIP_MEMORY_SCOPE_AGENT);
        u64 v1 = __hip_atomic_load(&s1[k], __ATOMIC_RELAXED, __HIP_MEMORY_SCOPE_AGENT);
        *(u64*)(h0s + d) = v0;
        *(u64*)(h1s + d) = v1;
      }
    }
    __syncthreads();

    // ---- dots: acc0 = wh0 . h0 ; acc1 = wx1 . h0 + wh1 . h1 (per batch) ----
    float acc0[BB], acc1[BB];
    #pragma unroll
    for (int b = 0; b < BB; ++b) {
      const __half* hp0 = h0s + b * BROW + ks * CH;
      f16x2 hh[32];
      #pragma unroll
      for (int q = 0; q < 8; ++q) {
        F4H t; t.f = *(const f32x4*)(hp0 + q * 8);
        hh[q * 4 + 0] = t.h[0]; hh[q * 4 + 1] = t.h[1];
        hh[q * 4 + 2] = t.h[2]; hh[q * 4 + 3] = t.h[3];
      }
      float a0 = 0.f, a1 = 0.f;
      #pragma unroll
      for (int j = 0; j < 32; ++j) { a0 = dot2f(w0[j], hh[j], a0); a1 = dot2f(w1[j], hh[j], a1); }
      const __half* hp1 = h1s + b * BROW + ks * CH;
      #pragma unroll
      for (int q = 0; q < 8; ++q) {
        F4H t; t.f = *(const f32x4*)(hp1 + q * 8);
        hh[q * 4 + 0] = t.h[0]; hh[q * 4 + 1] = t.h[1];
        hh[q * 4 + 2] = t.h[2]; hh[q * 4 + 3] = t.h[3];
      }
      #pragma unroll
      for (int j = 0; j < 32; ++j) { a1 = dot2f(w2[j], hh[j], a1); }
      acc0[b] = a0; acc1[b] = a1;
    }
    #pragma unroll
    for (int m = 1; m <= 8; m <<= 1) {
      #pragma unroll
      for (int b = 0; b < BB; ++b) {
        acc0[b] += __shfl_xor(acc0[b], m, 64);
        acc1[b] += __shfl_xor(acc1[b], m, 64);
      }
    }
    if (ks == 0) {
      #pragma unroll
      for (int b = 0; b < BB; ++b) {
        gx[rg * 8 + b]        = acc0[b];
        gx[(16 + rg) * 8 + b] = acc1[b];
      }
    }
    __syncthreads();

    // ---- cell/hidden update: 64 threads = 2 layers x 4 units x 8 batch ----
    if (tid < 64) {
      const int l = tid >> 5, uu = (tid >> 3) & 3, b = tid & 7;
      const bool act = (l == 0) ? (tau < TT) : (tau >= 1);
      float hn = 0.0f;
      if (act) {
        const float* gp = gx + ((l << 4) + (uu << 2)) * 8 + b;
        float gi = gp[0], gf = gp[8], gg_ = gp[16], go = gp[24];
        if (l == 0) { gi += x0r0; gf += x0r1; gg_ += x0r2; go += x0r3; }
        else        { gi += bi0;  gf += bi1;  gg_ += bi2;  go += bi3;  }
        const int u = u0 + uu;
        float* cp = cgl + (size_t)l * (HID * BB) + u * BB + b;
        float co = *cp;
        float cn = sigf(gf) * co + sigf(gi) * tanhf(gg_);
        hn = sigf(go) * tanhf(co);   // quirk: tanh of OLD cell
        *cp = cn;
      }
      float hpart = __shfl_xor(hn, 8, 64);     // partner unit (uu^1), same b/l
      if (act && !(uu & 1)) {
        const int u = u0 + uu;
        __half2 hp2 = __floats2half2_rn(hn, hpart);
        unsigned pv; __builtin_memcpy(&pv, &hp2, 4);
        if (l == 0) {
          unsigned* dst = (unsigned*)(h0t + (tau & 1) * (HID * BB)) + ((b * HID + u) >> 1);
          __hip_atomic_store(dst, pv, __ATOMIC_RELAXED, __HIP_MEMORY_SCOPE_AGENT);
        } else {
          unsigned* dst = (unsigned*)(h1t + ((tau - 1) & 1) * (HID * BB)) + ((b * HID + u) >> 1);
          __hip_atomic_store(dst, pv, __ATOMIC_RELAXED, __HIP_MEMORY_SCOPE_AGENT);
          *((unsigned*)outf + ((((size_t)b * TT + (tau - 1)) * HID + u) >> 1)) = pv;
        }
      }
    }
    if constexpr (COOP) gbar(bs, tau - tau0 + 1);
  }

  // final h, c
  if (tau1 > TT && tid < 64) {
    const int l = tid >> 5, uu = (tid >> 3) & 3, b = tid & 7;
    const int u = u0 + uu;
    const unsigned* src = (const unsigned*)((l == 0 ? h0t : h1t) + (HID * BB)) + ((b * HID + u) >> 1);
    unsigned pv = __hip_atomic_load(src, __ATOMIC_RELAXED, __HIP_MEMORY_SCOPE_AGENT);
    __half2 hp2; __builtin_memcpy(&hp2, &pv, 4);
    float hv = (u & 1) ? __high2float(hp2) : __low2float(hp2);
    hc_out[(size_t)l * (BB * HID) + b * HID + u] = hv;
    hc_out[2 * (BB * HID) + (size_t)l * (BB * HID) + b * HID + u] =
        cgl[(size_t)l * (HID * BB) + u * BB + b];
  }
}

extern "C" void kernel_launch(void* const* d_in, const int* in_sizes, int n_in,
                              void* d_out, int out_size, void* d_ws, size_t ws_size,
                              hipStream_t stream) {
  (void)in_sizes; (void)n_in; (void)out_size; (void)ws_size;
  const int*   x    = (const int*)  d_in[0];
  const float* embW = (const float*)d_in[1];
  const float* wxw  = (const float*)d_in[2];
  const float* wxb  = (const float*)d_in[3];
  const float* whw  = (const float*)d_in[4];
  float* out = (float*)d_out;

  char* ws = (char*)d_ws;
  size_t off = 0;
  auto alloc = [&](size_t bytes) { char* p = ws + off; off += (bytes + 255) & ~(size_t)255; return p; };
  __half*   emb16 = (__half*)alloc((size_t)VOCABN * HID * 2);
  __half*   xe16  = (__half*)alloc((size_t)4096 * HID * 2);
  __half*   wxw16 = (__half*)alloc((size_t)2 * G4 * HID * 2);
  __half*   whw16 = (__half*)alloc((size_t)2 * G4 * HID * 2);
  __half*   X0T   = (__half*)alloc((size_t)4096 * G4 * 2);
  __half*   outf  = (__half*)alloc((size_t)4096 * HID * 2);
  __half*   h0t   = (__half*)alloc((size_t)2 * HID * BB * 2);
  __half*   h1t   = (__half*)alloc((size_t)2 * HID * BB * 2);
  float*    cgl   = (float*) alloc((size_t)2 * HID * BB * 4);
  unsigned* bs    = (unsigned*)alloc(256);

  cvt_f16_kernel<<<2048, 256, 0, stream>>>(embW, emb16, VOCABN * HID / 4);
  cvt_f16_kernel<<<1024, 256, 0, stream>>>(wxw, wxw16, 2 * G4 * HID / 4);
  cvt_f16_kernel<<<1024, 256, 0, stream>>>(whw, whw16, 2 * G4 * HID / 4);
  gather_kernel<<<2048, 256, 0, stream>>>(x, emb16, xe16);
  hipMemsetAsync(h0t, 0, (size_t)2 * HID * BB * 2, stream);
  hipMemsetAsync(h1t, 0, (size_t)2 * HID * BB * 2, stream);
  hipMemsetAsync(cgl, 0, (size_t)2 * HID * BB * 4, stream);
  hipMemsetAsync(bs,  0, 256, stream);

  // X0T[tau][gate][unit][batch] = xe @ wx0^T + b0   (f16)
  gemm_f16_kernel<__half, true><<<dim3(32, 32), 256, 0, stream>>>(
      (const _Float16*)xe16, (const _Float16*)wxw16, X0T, wxb, G4);

  const __half* wh0 = whw16;
  const __half* wx1 = wxw16 + (size_t)G4 * HID;
  const __half* wh1 = whw16 + (size_t)G4 * HID;
  const __half* X0c = X0T;
  const float*  wxb1 = wxb + G4;
  float* hc = out + (size_t)4096 * VOCABN;
  int tb = 0, te = TT + 1;
  void* args[] = {(void*)&wh0, (void*)&wx1, (void*)&wh1, (void*)&X0c, (void*)&wxb1,
                  (void*)&h0t, (void*)&h1t, (void*)&cgl, (void*)&outf, (void*)&hc,
                  (void*)&bs, (void*)&tb, (void*)&te};
  hipError_t rc = hipLaunchCooperativeKernel(
      reinterpret_cast<void*>(&lstm_kernel<true>), dim3(256), dim3(256), args, 0, stream);
  if (rc != hipSuccess) {
    for (int tau = 0; tau <= TT; ++tau)
      lstm_kernel<false><<<256, 256, 0, stream>>>(wh0, wx1, wh1, X0c, wxb1,
                                                  h0t, h1t, cgl, outf, hc, bs, tau, tau + 1);
  }

  // logits = out_h1 @ emb^T  (f32)
  gemm_f16_kernel<float, false><<<dim3(250, 32), 256, 0, stream>>>(
      (const _Float16*)outf, (const _Float16*)emb16, out, nullptr, VOCABN);
}

// Round 5
// 6591.112 us; speedup vs baseline: 4.4058x; 1.0739x over previous
//
#include <hip/hip_runtime.h>
#include <hip/hip_fp16.h>

#define HID    1024
#define G4     4096
#define TT     512
#define BB     8
#define VOCABN 32000
#define CH     72     // LDS chunk stride (halves) per 64-col chunk
#define BROW   1160   // LDS halves per batch row: 16*CH + 8 pad
#define NBLK   256

typedef _Float16 f16x2 __attribute__((ext_vector_type(2)));
typedef _Float16 f16x8 __attribute__((ext_vector_type(8)));
typedef float    f32x4 __attribute__((ext_vector_type(4)));
typedef unsigned long long u64;

union F4H { f32x4 f; f16x2 h[4]; };

__device__ __forceinline__ float dot2f(f16x2 a, f16x2 b, float c) {
#if __has_builtin(__builtin_amdgcn_fdot2)
  return __builtin_amdgcn_fdot2(a, b, c, false);
#else
  return c + (float)a[0] * (float)b[0] + (float)a[1] * (float)b[1];
#endif
}
__device__ __forceinline__ float sigf(float x) { return 1.0f / (1.0f + expf(-x)); }

// ---------------- f32 -> f16 convert ----------------
__global__ void cvt_f16_kernel(const float* __restrict__ src, __half* __restrict__ dst, int n4) {
  int i = blockIdx.x * blockDim.x + threadIdx.x;
  int stride = gridDim.x * blockDim.x;
  for (; i < n4; i += stride) {
    f32x4 v = ((const f32x4*)src)[i];
    ((__half2*)dst)[2 * i]     = __floats2half2_rn(v[0], v[1]);
    ((__half2*)dst)[2 * i + 1] = __floats2half2_rn(v[2], v[3]);
  }
}

// ---------------- embedding gather: xe[t*8+b] = emb16[x[b][t]] ----------------
__global__ void gather_kernel(const int* __restrict__ x, const __half* __restrict__ emb,
                              __half* __restrict__ xe) {
  int gid = blockIdx.x * 256 + threadIdx.x;   // 4096 rows * 128 chunks of 16B
  int row = gid >> 7, ch = gid & 127;
  int t = row >> 3, b = row & 7;
  int tok = x[b * TT + t];
  ((f32x4*)(xe + (size_t)row * HID))[ch] = ((const f32x4*)(emb + (size_t)tok * HID))[ch];
}

__device__ __forceinline__ void storeC(float* p, float v)  { *p = v; }
__device__ __forceinline__ void storeC(__half* p, float v) { *p = __float2half(v); }

// ------- 128x128 f16 MFMA GEMM: C = A[M,1024] * B[N,1024]^T (+bias) -------
// XL=true: write to X0T layout [tau][gate][unit][batch] (half)
template <typename CT, bool XL>
__global__ void __launch_bounds__(256) gemm_f16_kernel(
    const _Float16* __restrict__ A, const _Float16* __restrict__ B,
    CT* __restrict__ C, const float* __restrict__ bias, int N)
{
  __shared__ _Float16 As[128 * 40];
  __shared__ _Float16 Bs[128 * 40];
  const int tid = threadIdx.x;
  const int tn = blockIdx.x, tm = blockIdx.y;
  const int wave = tid >> 6, lane = tid & 63;
  const int wm = wave >> 1, wn = wave & 1;
  const int lr = lane & 15, lk = ((lane >> 4) << 3);
  const _Float16* Ab = A + (size_t)tm * 128 * HID;
  const _Float16* Bb = B + (size_t)tn * 128 * HID;
  const int r0 = tid >> 2, c8 = (tid & 3) * 8;
  f32x4 acc[4][4] = {};
  f32x4 a0r, a1r, b0r, b1r;
  a0r = *(const f32x4*)(Ab + (size_t)r0 * HID + c8);
  a1r = *(const f32x4*)(Ab + (size_t)(64 + r0) * HID + c8);
  b0r = *(const f32x4*)(Bb + (size_t)r0 * HID + c8);
  b1r = *(const f32x4*)(Bb + (size_t)(64 + r0) * HID + c8);
  for (int kt = 0; kt < 32; ++kt) {
    __syncthreads();
    *(f32x4*)(As + (size_t)r0 * 40 + c8)        = a0r;
    *(f32x4*)(As + (size_t)(64 + r0) * 40 + c8) = a1r;
    *(f32x4*)(Bs + (size_t)r0 * 40 + c8)        = b0r;
    *(f32x4*)(Bs + (size_t)(64 + r0) * 40 + c8) = b1r;
    __syncthreads();
    if (kt < 31) {
      int ko = (kt + 1) * 32 + c8;
      a0r = *(const f32x4*)(Ab + (size_t)r0 * HID + ko);
      a1r = *(const f32x4*)(Ab + (size_t)(64 + r0) * HID + ko);
      b0r = *(const f32x4*)(Bb + (size_t)r0 * HID + ko);
      b1r = *(const f32x4*)(Bb + (size_t)(64 + r0) * HID + ko);
    }
    f16x8 af[4], bf[4];
    #pragma unroll
    for (int m = 0; m < 4; ++m) af[m] = *(const f16x8*)(As + (wm * 64 + m * 16 + lr) * 40 + lk);
    #pragma unroll
    for (int n = 0; n < 4; ++n) bf[n] = *(const f16x8*)(Bs + (wn * 64 + n * 16 + lr) * 40 + lk);
    #pragma unroll
    for (int m = 0; m < 4; ++m)
      #pragma unroll
      for (int n = 0; n < 4; ++n)
        acc[m][n] = __builtin_amdgcn_mfma_f32_16x16x32_f16(af[m], bf[n], acc[m][n], 0, 0, 0);
  }
  const int mrow = ((lane >> 4) << 2);
  #pragma unroll
  for (int n = 0; n < 4; ++n) {
    int gc = tn * 128 + wn * 64 + n * 16 + lr;
    float bc = bias ? bias[gc] : 0.0f;
    #pragma unroll
    for (int m = 0; m < 4; ++m) {
      int gr0 = tm * 128 + wm * 64 + m * 16 + mrow;
      #pragma unroll
      for (int r = 0; r < 4; ++r) {
        float v = acc[m][n][r] + bc;
        if constexpr (XL) {
          int gr = gr0 + r;
          int idx = ((gr >> 3) * 4 + (gc >> 10)) * 8192 + (gc & 1023) * 8 + (gr & 7);
          storeC(C + idx, v);
        } else {
          storeC(C + (size_t)(gr0 + r) * N + gc, v);
        }
      }
    }
  }
}

// ---- flat fence-free grid barrier: store own flag, poll all 256 ----
// Arrival: one relaxed agent store (no RMW contention). Detection: wave 0 of
// every block loads all 256 flags (2 u64/lane) and __all-reduces. Critical
// path = 2 LLC hops. Timeout guard: fail loud, never hang.
__device__ __forceinline__ void gbar(unsigned* flags, int tick) {
  __syncthreads();   // all waves done reading prev-tick state
  const int tid = threadIdx.x;
  if (tid < 64) {    // wave 0 (also the wave that issued the h stores)
    asm volatile("s_waitcnt vmcnt(0)" ::: "memory");   // h stores acked at LLC
    if (tid == 0)
      __hip_atomic_store(&flags[blockIdx.x], (unsigned)tick,
                         __ATOMIC_RELAXED, __HIP_MEMORY_SCOPE_AGENT);
    const u64* fp = (const u64*)flags;   // 128 u64 spans 256 u32 flags
    int guard = 0;
    for (;;) {
      u64 a = __hip_atomic_load(&fp[tid],      __ATOMIC_RELAXED, __HIP_MEMORY_SCOPE_AGENT);
      u64 b = __hip_atomic_load(&fp[tid + 64], __ATOMIC_RELAXED, __HIP_MEMORY_SCOPE_AGENT);
      bool ok = ((unsigned)a >= (unsigned)tick) && ((unsigned)(a >> 32) >= (unsigned)tick) &&
                ((unsigned)b >= (unsigned)tick) && ((unsigned)(b >> 32) >= (unsigned)tick);
      if (__all(ok)) break;
      if (++guard > 100000) break;       // failsafe: wrong answer, not a hang
      __builtin_amdgcn_s_sleep(1);
    }
  }
  __syncthreads();
}

// ---------------- persistent LSTM ----------------
// 256 WGs x 256 threads. WG owns 4 units/layer; weights in regs (96 f16x2 x3).
// h state global f16 double-buffered, exchanged via relaxed agent atomics (LLC).
// Tick tau: layer0 -> h0[tau] (tau<512); layer1 -> h1[tau-1] (tau>=1).
template <bool COOP>
__global__ void __launch_bounds__(256, 2) lstm_kernel(
    const __half* __restrict__ wh0, const __half* __restrict__ wx1, const __half* __restrict__ wh1,
    const __half* __restrict__ X0T, const float* __restrict__ wxb1,
    __half* __restrict__ h0t, __half* __restrict__ h1t, float* __restrict__ cgl,
    __half* __restrict__ outf, float* __restrict__ hc_out, unsigned* __restrict__ bs,
    int tau0, int tau1)
{
  __shared__ __half h0s[BB * BROW];
  __shared__ __half h1s[BB * BROW];
  __shared__ float  gx[32 * 8];

  const int tid = threadIdx.x;
  const int u0  = blockIdx.x * 4;
  const int rg  = tid >> 4, ks = tid & 15;   // rg: g=rg&3, uu=rg>>2 ; ks: 64-col k-slice

  // ---- pin weights in registers: 3 x 32 f16x2 per thread ----
  f16x2 w0[32], w1[32], w2[32];
  {
    const int r = (rg & 3) * HID + u0 + (rg >> 2);
    const __half* p0 = wh0 + (size_t)r * HID + ks * 64;
    const __half* p1 = wx1 + (size_t)r * HID + ks * 64;
    const __half* p2 = wh1 + (size_t)r * HID + ks * 64;
    #pragma unroll
    for (int q = 0; q < 8; ++q) {
      F4H t0, t1, t2;
      t0.f = *(const f32x4*)(p0 + q * 8);
      t1.f = *(const f32x4*)(p1 + q * 8);
      t2.f = *(const f32x4*)(p2 + q * 8);
      #pragma unroll
      for (int j = 0; j < 4; ++j) {
        w0[q * 4 + j] = t0.h[j]; w1[q * 4 + j] = t1.h[j]; w2[q * 4 + j] = t2.h[j];
      }
    }
  }

  float bi0 = 0, bi1 = 0, bi2 = 0, bi3 = 0;
  if (tid >= 32 && tid < 64) {
    int uu = (tid >> 3) & 3, u = u0 + uu;
    bi0 = wxb1[u]; bi1 = wxb1[HID + u]; bi2 = wxb1[2 * HID + u]; bi3 = wxb1[3 * HID + u];
  }

  for (int tau = tau0; tau < tau1; ++tau) {
    // X0 prefetch (coalesced: 32 consecutive halves per gate)
    float x0r0 = 0, x0r1 = 0, x0r2 = 0, x0r3 = 0;
    if (tid < 32 && tau < TT) {
      const __half* xp = X0T + (size_t)tau * 4 * 8192 + u0 * 8 + tid;
      x0r0 = __half2float(xp[0]);
      x0r1 = __half2float(xp[8192]);
      x0r2 = __half2float(xp[2 * 8192]);
      x0r3 = __half2float(xp[3 * 8192]);
    }
    // stage h0[tau-1], h1[tau-2] into chunk-padded LDS (coherent u64 loads from LLC)
    {
      const u64* s0 = (const u64*)(h0t + ((tau - 1) & 1) * (HID * BB));
      const u64* s1 = (const u64*)(h1t + (tau & 1) * (HID * BB));
      #pragma unroll
      for (int i = 0; i < 8; ++i) {
        int k = i * 256 + tid;           // 2048 u64 granules per buffer
        int b = k >> 8, q = k & 255;
        int d = b * BROW + (q >> 4) * CH + (q & 15) * 4;
        u64 v0 = __hip_atomic_load(&s0[k], __ATOMIC_RELAXED, __HIP_MEMORY_SCOPE_AGENT);
        u64 v1 = __hip_atomic_load(&s1[k], __ATOMIC_RELAXED, __HIP_MEMORY_SCOPE_AGENT);
        *(u64*)(h0s + d) = v0;
        *(u64*)(h1s + d) = v1;
      }
    }
    __syncthreads();

    // ---- dots: acc0 = wh0 . h0 ; acc1 = wx1 . h0 + wh1 . h1 (per batch) ----
    float acc0[BB], acc1[BB];
    #pragma unroll
    for (int b = 0; b < BB; ++b) {
      const __half* hp0 = h0s + b * BROW + ks * CH;
      f16x2 hh[32];
      #pragma unroll
      for (int q = 0; q < 8; ++q) {
        F4H t; t.f = *(const f32x4*)(hp0 + q * 8);
        hh[q * 4 + 0] = t.h[0]; hh[q * 4 + 1] = t.h[1];
        hh[q * 4 + 2] = t.h[2]; hh[q * 4 + 3] = t.h[3];
      }
      float a0 = 0.f, a1 = 0.f;
      #pragma unroll
      for (int j = 0; j < 32; ++j) { a0 = dot2f(w0[j], hh[j], a0); a1 = dot2f(w1[j], hh[j], a1); }
      const __half* hp1 = h1s + b * BROW + ks * CH;
      #pragma unroll
      for (int q = 0; q < 8; ++q) {
        F4H t; t.f = *(const f32x4*)(hp1 + q * 8);
        hh[q * 4 + 0] = t.h[0]; hh[q * 4 + 1] = t.h[1];
        hh[q * 4 + 2] = t.h[2]; hh[q * 4 + 3] = t.h[3];
      }
      #pragma unroll
      for (int j = 0; j < 32; ++j) { a1 = dot2f(w2[j], hh[j], a1); }
      acc0[b] = a0; acc1[b] = a1;
    }
    #pragma unroll
    for (int m = 1; m <= 8; m <<= 1) {
      #pragma unroll
      for (int b = 0; b < BB; ++b) {
        acc0[b] += __shfl_xor(acc0[b], m, 64);
        acc1[b] += __shfl_xor(acc1[b], m, 64);
      }
    }
    if (ks == 0) {
      #pragma unroll
      for (int b = 0; b < BB; ++b) {
        gx[rg * 8 + b]        = acc0[b];
        gx[(16 + rg) * 8 + b] = acc1[b];
      }
    }
    __syncthreads();

    // ---- cell/hidden update: 64 threads = 2 layers x 4 units x 8 batch ----
    if (tid < 64) {
      const int l = tid >> 5, uu = (tid >> 3) & 3, b = tid & 7;
      const bool act = (l == 0) ? (tau < TT) : (tau >= 1);
      float hn = 0.0f;
      if (act) {
        const float* gp = gx + ((l << 4) + (uu << 2)) * 8 + b;
        float gi = gp[0], gf = gp[8], gg_ = gp[16], go = gp[24];
        if (l == 0) { gi += x0r0; gf += x0r1; gg_ += x0r2; go += x0r3; }
        else        { gi += bi0;  gf += bi1;  gg_ += bi2;  go += bi3;  }
        const int u = u0 + uu;
        float* cp = cgl + (size_t)l * (HID * BB) + u * BB + b;
        float co = *cp;
        float cn = sigf(gf) * co + sigf(gi) * tanhf(gg_);
        hn = sigf(go) * tanhf(co);   // quirk: tanh of OLD cell
        *cp = cn;
      }
      float hpart = __shfl_xor(hn, 8, 64);     // partner unit (uu^1), same b/l
      if (act && !(uu & 1)) {
        const int u = u0 + uu;
        __half2 hp2 = __floats2half2_rn(hn, hpart);
        unsigned pv; __builtin_memcpy(&pv, &hp2, 4);
        if (l == 0) {
          unsigned* dst = (unsigned*)(h0t + (tau & 1) * (HID * BB)) + ((b * HID + u) >> 1);
          __hip_atomic_store(dst, pv, __ATOMIC_RELAXED, __HIP_MEMORY_SCOPE_AGENT);
        } else {
          unsigned* dst = (unsigned*)(h1t + ((tau - 1) & 1) * (HID * BB)) + ((b * HID + u) >> 1);
          __hip_atomic_store(dst, pv, __ATOMIC_RELAXED, __HIP_MEMORY_SCOPE_AGENT);
          *((unsigned*)outf + ((((size_t)b * TT + (tau - 1)) * HID + u) >> 1)) = pv;
        }
      }
    }
    if constexpr (COOP) gbar(bs, tau - tau0 + 1);
  }

  // final h, c
  if (tau1 > TT && tid < 64) {
    const int l = tid >> 5, uu = (tid >> 3) & 3, b = tid & 7;
    const int u = u0 + uu;
    const unsigned* src = (const unsigned*)((l == 0 ? h0t : h1t) + (HID * BB)) + ((b * HID + u) >> 1);
    unsigned pv = __hip_atomic_load(src, __ATOMIC_RELAXED, __HIP_MEMORY_SCOPE_AGENT);
    __half2 hp2; __builtin_memcpy(&hp2, &pv, 4);
    float hv = (u & 1) ? __high2float(hp2) : __low2float(hp2);
    hc_out[(size_t)l * (BB * HID) + b * HID + u] = hv;
    hc_out[2 * (BB * HID) + (size_t)l * (BB * HID) + b * HID + u] =
        cgl[(size_t)l * (HID * BB) + u * BB + b];
  }
}

extern "C" void kernel_launch(void* const* d_in, const int* in_sizes, int n_in,
                              void* d_out, int out_size, void* d_ws, size_t ws_size,
                              hipStream_t stream) {
  (void)in_sizes; (void)n_in; (void)out_size; (void)ws_size;
  const int*   x    = (const int*)  d_in[0];
  const float* embW = (const float*)d_in[1];
  const float* wxw  = (const float*)d_in[2];
  const float* wxb  = (const float*)d_in[3];
  const float* whw  = (const float*)d_in[4];
  float* out = (float*)d_out;

  char* ws = (char*)d_ws;
  size_t off = 0;
  auto alloc = [&](size_t bytes) { char* p = ws + off; off += (bytes + 255) & ~(size_t)255; return p; };
  __half*   emb16 = (__half*)alloc((size_t)VOCABN * HID * 2);
  __half*   xe16  = (__half*)alloc((size_t)4096 * HID * 2);
  __half*   wxw16 = (__half*)alloc((size_t)2 * G4 * HID * 2);
  __half*   whw16 = (__half*)alloc((size_t)2 * G4 * HID * 2);
  __half*   X0T   = (__half*)alloc((size_t)4096 * G4 * 2);
  __half*   outf  = (__half*)alloc((size_t)4096 * HID * 2);
  __half*   h0t   = (__half*)alloc((size_t)2 * HID * BB * 2);
  __half*   h1t   = (__half*)alloc((size_t)2 * HID * BB * 2);
  float*    cgl   = (float*) alloc((size_t)2 * HID * BB * 4);
  unsigned* bs    = (unsigned*)alloc(NBLK * 4);

  cvt_f16_kernel<<<2048, 256, 0, stream>>>(embW, emb16, VOCABN * HID / 4);
  cvt_f16_kernel<<<1024, 256, 0, stream>>>(wxw, wxw16, 2 * G4 * HID / 4);
  cvt_f16_kernel<<<1024, 256, 0, stream>>>(whw, whw16, 2 * G4 * HID / 4);
  gather_kernel<<<2048, 256, 0, stream>>>(x, emb16, xe16);
  hipMemsetAsync(h0t, 0, (size_t)2 * HID * BB * 2, stream);
  hipMemsetAsync(h1t, 0, (size_t)2 * HID * BB * 2, stream);
  hipMemsetAsync(cgl, 0, (size_t)2 * HID * BB * 4, stream);
  hipMemsetAsync(bs,  0, NBLK * 4, stream);

  // X0T[tau][gate][unit][batch] = xe @ wx0^T + b0   (f16)
  gemm_f16_kernel<__half, true><<<dim3(32, 32), 256, 0, stream>>>(
      (const _Float16*)xe16, (const _Float16*)wxw16, X0T, wxb, G4);

  const __half* wh0 = whw16;
  const __half* wx1 = wxw16 + (size_t)G4 * HID;
  const __half* wh1 = whw16 + (size_t)G4 * HID;
  const __half* X0c = X0T;
  const float*  wxb1 = wxb + G4;
  float* hc = out + (size_t)4096 * VOCABN;
  int tb = 0, te = TT + 1;
  void* args[] = {(void*)&wh0, (void*)&wx1, (void*)&wh1, (void*)&X0c, (void*)&wxb1,
                  (void*)&h0t, (void*)&h1t, (void*)&cgl, (void*)&outf, (void*)&hc,
                  (void*)&bs, (void*)&tb, (void*)&te};
  hipError_t rc = hipLaunchCooperativeKernel(
      reinterpret_cast<void*>(&lstm_kernel<true>), dim3(NBLK), dim3(256), args, 0, stream);
  if (rc != hipSuccess) {
    for (int tau = 0; tau <= TT; ++tau)
      lstm_kernel<false><<<NBLK, 256, 0, stream>>>(wh0, wx1, wh1, X0c, wxb1,
                                                   h0t, h1t, cgl, outf, hc, bs, tau, tau + 1);
  }

  // logits = out_h1 @ emb^T  (f32)
  gemm_f16_kernel<float, false><<<dim3(250, 32), 256, 0, stream>>>(
      (const _Float16*)outf, (const _Float16*)emb16, out, nullptr, VOCABN);
}